// Round 1
// baseline (190.941 us; speedup 1.0000x reference)
//
#include <hip/hip_runtime.h>

// CompanionSSM, one launch: one block (8 waves, 512 thr) per head.
// Whole-sequence restructure: G(128x128 bf16) built in LDS (prep without
// in-loop reductions), A-frags to registers, T8 = (A^64)^8 via 3 MFMA
// squarings (hi/lo bf16 split, tiles spread over 8 waves). Then:
//   Phase A : each wave loads its 8 chunks (float4 + DPP 4x4 transpose,
//             depth-3 pipeline), keeps U B-frags in regs, R=V@U -> slots
//   pass1   : per-wave serial local scan (8 it) -> group Rsum -> Gsum[w]
//   pass2   : wave 0 scans 8 group summaries with T8 -> group states
//   pass3+C : per-wave re-scan seeded with group state; Y = W@S + Toep@U
//             fused per chunk, DPP transpose -> dwordx4 stores
// C->B-frag conversion via 16 ds_bpermute (no Xk buffer).
// LDS: 64 R slots (128KB, aliases G + squaring scratch) + Gsum 16KB + phi/kv.

#define NKH 256
#define KD  64
#define SL  4096
#define DM  1024

typedef __attribute__((ext_vector_type(8))) short short8;
typedef __attribute__((ext_vector_type(4))) float floatx4;

#define LDS_GSUM  131072
#define LDS_PHI   147456
#define LDS_KV    147968
#define LDS_TOTAL 148224
#define SCRA_OFF  32768
#define SCRB_OFF  50176
#define SCR_STR   68

static __device__ __forceinline__ unsigned pack_bf16(float a, float b) {
  union { float f; unsigned u; } ua, ub;
  ua.f = a; ub.f = b;
  return __builtin_amdgcn_perm(ub.u + 0x8000u, ua.u + 0x8000u, 0x07060302u);
}
static __device__ __forceinline__ unsigned short f2bfru(float x) {
  union { float f; unsigned u; } v; v.f = x;
  return (unsigned short)((v.u + 0x8000u) >> 16);
}
static __device__ __forceinline__ float bflo(unsigned d) {
  union { unsigned u; float f; } v; v.u = d << 16; return v.f;
}
static __device__ __forceinline__ float bfhi(unsigned d) {
  union { unsigned u; float f; } v; v.u = d & 0xffff0000u; return v.f;
}
static __device__ __forceinline__ float bf2f(unsigned short s) {
  union { unsigned u; float f; } v; v.u = ((unsigned)s) << 16; return v.f;
}
static __device__ __forceinline__ float wredsum(float x) {
#pragma unroll
  for (int off = 32; off; off >>= 1) x += __shfl_xor(x, off, 64);
  return x;
}
// 4x4 transpose across a DPP quad (lanes 4k..4k+3, c = lane&3).
// Input: lane c holds v[0..3] = M[c][*].  Output: r[k] = M[k][c].
static __device__ __forceinline__ float4 qtr(float4 v, int c) {
  const bool c1 = (c & 1) != 0, c2 = (c & 2) != 0;
  float a01 = __shfl_xor(v.y, 1, 64), a10 = __shfl_xor(v.x, 1, 64);
  float a23 = __shfl_xor(v.w, 1, 64), a32 = __shfl_xor(v.z, 1, 64);
  float t0 = c1 ? a01 : v.x, t1 = c1 ? v.y : a10;
  float t2 = c1 ? a23 : v.z, t3 = c1 ? v.w : a32;
  float b02 = __shfl_xor(t2, 2, 64), b20 = __shfl_xor(t0, 2, 64);
  float b13 = __shfl_xor(t3, 2, 64), b31 = __shfl_xor(t1, 2, 64);
  float4 r;
  r.x = c2 ? b02 : t0; r.y = c2 ? b13 : t1;
  r.z = c2 ? t2 : b20; r.w = c2 ? t3 : b31;
  return r;
}

// One squaring level: DST = SRC @ SRC (64x64 f32 in LDS), hi/lo bf16 split
// (error ~ (2^-8)^2).  16 output tiles split as 2 per wave.
#define SQ_LEVEL(SRC, DST) do { \
  _Pragma("unroll") \
  for (int tt_ = 0; tt_ < 2; ++tt_) { \
    const int rt_ = (2*w + tt_) >> 2, ct_ = (2*w + tt_) & 3; \
    short8 Ah_[2], Al_[2], Bh_[2], Bl_[2]; \
    _Pragma("unroll") \
    for (int kt_ = 0; kt_ < 2; ++kt_) { \
      const float* ap_ = (SRC) + (16*rt_ + n16)*SCR_STR + 32*kt_ + 8*quad; \
      union { short8 v; unsigned short us[8]; } ah_, al_, bh_, bl_; \
      _Pragma("unroll") \
      for (int j_ = 0; j_ < 8; ++j_) { \
        float x_ = ap_[j_]; \
        unsigned short hu_ = f2bfru(x_); \
        ah_.us[j_] = (short)hu_; al_.us[j_] = (short)f2bfru(x_ - bf2f(hu_)); \
      } \
      _Pragma("unroll") \
      for (int j_ = 0; j_ < 8; ++j_) { \
        float x_ = (SRC)[(32*kt_ + 8*quad + j_)*SCR_STR + 16*ct_ + n16]; \
        unsigned short hu_ = f2bfru(x_); \
        bh_.us[j_] = (short)hu_; bl_.us[j_] = (short)f2bfru(x_ - bf2f(hu_)); \
      } \
      Ah_[kt_] = ah_.v; Al_[kt_] = al_.v; Bh_[kt_] = bh_.v; Bl_[kt_] = bl_.v; \
    } \
    floatx4 d_ = {0.f, 0.f, 0.f, 0.f}; \
    _Pragma("unroll") \
    for (int kt_ = 0; kt_ < 2; ++kt_) { \
      d_ = __builtin_amdgcn_mfma_f32_16x16x32_bf16(Ah_[kt_], Bh_[kt_], d_, 0,0,0); \
      d_ = __builtin_amdgcn_mfma_f32_16x16x32_bf16(Ah_[kt_], Bl_[kt_], d_, 0,0,0); \
      d_ = __builtin_amdgcn_mfma_f32_16x16x32_bf16(Al_[kt_], Bh_[kt_], d_, 0,0,0); \
    } \
    _Pragma("unroll") \
    for (int r_ = 0; r_ < 4; ++r_) \
      (DST)[(16*rt_ + 4*quad + r_)*SCR_STR + 16*ct_ + n16] = d_[r_]; \
  } \
} while (0)

// Load chunk J (rows q0+64J .. +63, 4 batches, 4 channels) as 4 float4/lane.
#define LOADC(J, VA) do { \
  const float* p_ = ubase + (size_t)(q0 + (J)*64 + tof) * DM; \
  VA[0][0] = *(const float4*)(p_); \
  VA[0][1] = *(const float4*)(p_ + (size_t)4  * DM); \
  VA[1][0] = *(const float4*)(p_ + (size_t)32 * DM); \
  VA[1][1] = *(const float4*)(p_ + (size_t)36 * DM); \
} while (0)

// Transpose chunk J to U B-frags (kept in UB[J]), R = V@U -> slot.
#define PROCC(J, VA) do { \
  _Pragma("unroll") \
  for (int kt_ = 0; kt_ < 2; ++kt_) { \
    float4 W0_ = qtr(VA[kt_][0], cc); \
    float4 W1_ = qtr(VA[kt_][1], cc); \
    union { short8 v; unsigned uu[4]; } ub_; \
    ub_.uu[0] = pack_bf16(W0_.x, W0_.y); ub_.uu[1] = pack_bf16(W0_.z, W0_.w); \
    ub_.uu[2] = pack_bf16(W1_.x, W1_.y); ub_.uu[3] = pack_bf16(W1_.z, W1_.w); \
    UB[J][kt_] = ub_.v; \
  } \
  char* slot_ = myslots + (J)*2048; \
  _Pragma("unroll") \
  for (int rt_ = 0; rt_ < 4; ++rt_) { \
    floatx4 r_ = {0.f, 0.f, 0.f, 0.f}; \
    r_ = __builtin_amdgcn_mfma_f32_16x16x32_bf16(Av[rt_][0], UB[J][0], r_, 0,0,0); \
    r_ = __builtin_amdgcn_mfma_f32_16x16x32_bf16(Av[rt_][1], UB[J][1], r_, 0,0,0); \
    uint2 pk_; pk_.x = pack_bf16(r_[0], r_[1]); pk_.y = pack_bf16(r_[2], r_[3]); \
    *(uint2*)(slot_ + rt_*512 + lane*8) = pk_; \
  } \
} while (0)

// One scan step: read R/Rsum (pk layout) from PTR, optionally write current
// S (B0,B1) over it, acc = T@S + C, convert C-layout -> B-frags via bpermute.
#define SCAN_STEP(PTR, ATM, WRS, WRPK, PKDST) do { \
  uint2 rb_[4]; \
  _Pragma("unroll") \
  for (int rt_ = 0; rt_ < 4; ++rt_) rb_[rt_] = *(const uint2*)((PTR) + rt_*512 + lane*8); \
  if (WRS) { \
    asm volatile("" ::: "memory"); \
    *(short8*)((PTR) + lane*16) = B0; \
    *(short8*)((PTR) + 1024 + lane*16) = B1; \
  } \
  floatx4 acc_[4]; \
  _Pragma("unroll") \
  for (int rt_ = 0; rt_ < 4; ++rt_) { \
    floatx4 cs_; \
    cs_[0] = bflo(rb_[rt_].x); cs_[1] = bfhi(rb_[rt_].x); \
    cs_[2] = bflo(rb_[rt_].y); cs_[3] = bfhi(rb_[rt_].y); \
    floatx4 a0_ = __builtin_amdgcn_mfma_f32_16x16x32_bf16(ATM[rt_][0], B0, cs_, 0,0,0); \
    acc_[rt_]  = __builtin_amdgcn_mfma_f32_16x16x32_bf16(ATM[rt_][1], B1, a0_, 0,0,0); \
  } \
  unsigned pk_[4][2]; \
  _Pragma("unroll") \
  for (int rt_ = 0; rt_ < 4; ++rt_) { \
    pk_[rt_][0] = pack_bf16(acc_[rt_][0], acc_[rt_][1]); \
    pk_[rt_][1] = pack_bf16(acc_[rt_][2], acc_[rt_][3]); \
  } \
  if (WRPK) { \
    _Pragma("unroll") \
    for (int rt_ = 0; rt_ < 4; ++rt_) { \
      uint2 pq_; pq_.x = pk_[rt_][0]; pq_.y = pk_[rt_][1]; \
      *(uint2*)((PKDST) + rt_*512 + lane*8) = pq_; \
    } \
  } \
  { union { short8 v; unsigned uu[4]; } nb0_, nb1_; \
    unsigned xa_, xb_; \
    xa_ = __shfl(pk_[0][0], srcA, 64); xb_ = __shfl(pk_[1][0], srcA, 64); nb0_.uu[0] = hi ? xb_ : xa_; \
    xa_ = __shfl(pk_[0][1], srcA, 64); xb_ = __shfl(pk_[1][1], srcA, 64); nb0_.uu[1] = hi ? xb_ : xa_; \
    xa_ = __shfl(pk_[0][0], srcB, 64); xb_ = __shfl(pk_[1][0], srcB, 64); nb0_.uu[2] = hi ? xb_ : xa_; \
    xa_ = __shfl(pk_[0][1], srcB, 64); xb_ = __shfl(pk_[1][1], srcB, 64); nb0_.uu[3] = hi ? xb_ : xa_; \
    xa_ = __shfl(pk_[2][0], srcA, 64); xb_ = __shfl(pk_[3][0], srcA, 64); nb1_.uu[0] = hi ? xb_ : xa_; \
    xa_ = __shfl(pk_[2][1], srcA, 64); xb_ = __shfl(pk_[3][1], srcA, 64); nb1_.uu[1] = hi ? xb_ : xa_; \
    xa_ = __shfl(pk_[2][0], srcB, 64); xb_ = __shfl(pk_[3][0], srcB, 64); nb1_.uu[2] = hi ? xb_ : xa_; \
    xa_ = __shfl(pk_[2][1], srcB, 64); xb_ = __shfl(pk_[3][1], srcB, 64); nb1_.uu[3] = hi ? xb_ : xa_; \
    B0 = nb0_.v; B1 = nb1_.v; } \
} while (0)

__global__ __launch_bounds__(512, 1) void fused_kernel(
    const float* __restrict__ u, const float* __restrict__ ga,
    const float* __restrict__ gb, const float* __restrict__ gc,
    float* __restrict__ out)
{
  __shared__ __align__(16) char lds[LDS_TOTAL];
  unsigned short* G = (unsigned short*)lds;     // 128x128 bf16, stride 128
  float* phi  = (float*)(lds + LDS_PHI);
  float* kv   = (float*)(lds + LDS_KV);
  float* scrA = (float*)(lds + SCRA_OFF);       // 64x68 f32 (T, T4)
  float* scrB = (float*)(lds + SCRB_OFF);       // 64x68 f32 (T2, T8)

  const int i = blockIdx.x;
  const int h = 8 * (i & 31) + (i >> 5);        // heads 8g..8g+7 -> same XCD
  const int t = threadIdx.x;
  const int w = t >> 6, lane = t & 63;
  const int n16 = lane & 15, quad = lane >> 4;
  const int bq = (lane >> 2) & 3, cc = lane & 3;

  // ---------------- prep chains (no in-loop reductions) ----------------
  if (w < 2) {
    const float av = ga[h*KD + lane];
    const float an = av / wredsum(fabsf(av));
    if (w == 1) {
      phi[lane] = gc[h*KD + lane];               // phi[0..63] = c
      float g = an;                              // g_64 = A^64 e0 = a_n
      for (int p = 64; p < 128; ++p) {
        G[(64 + lane)*128 + (p - 64)] = f2bfru(g);   // T col m = g_{64+m}
        const float top = __shfl(g, 63, 64);
        const float gm1 = __shfl_up(g, 1, 64);
        g = (lane > 0 ? gm1 : 0.0f) + an * top;
      }
    } else {
      float v = gb[h*KD + lane];                 // v_j = A^j b
      for (int j = 0; j < KD; ++j) {
        G[(64 + lane)*128 + 64 + (63 - j)] = f2bfru(v);  // V col m = v_{63-m}
        const float top = __shfl(v, 63, 64);
        const float vm1 = __shfl_up(v, 1, 64);
        v = (lane > 0 ? vm1 : 0.0f) + an * top;
      }
    }
  }
  __syncthreads();

  // ------- deferred dot products: phi[64..127] and kv[0..63] -------
  if (t < 128) {
    float acc = 0.f;
    for (int n = 0; n < 64; ++n)
      acc += phi[n] * bf2f(G[(64 + n)*128 + t]);
    if (t < 64) phi[64 + t] = acc;      // phi[p] = c . g_p
    else        kv[127 - t] = acc;      // kv[j] = c . v_j  (col 64+m = v_{63-m})
  }
  __syncthreads();

  // W block: G[j][i] = phi[j+1+i];  Toeplitz: G[j][64+m] = (m<=j)? kv[j-m] : 0
  for (int idx = t; idx < 4096; idx += 512) {
    const int j = idx >> 6, ii = idx & 63;
    G[j*128 + ii] = f2bfru(phi[j + 1 + ii]);
  }
  for (int idx = t; idx < 4096; idx += 512) {
    const int j = idx >> 6, m = idx & 63;
    G[j*128 + 64 + m] = (m <= j) ? f2bfru(kv[j - m]) : (unsigned short)0;
  }
  __syncthreads();

  // ---------------- extract A-fragments; copy T -> scrA (f32) ----------------
  short8 Aw[4][2], Ap[4][2], Av[4][2], At[4][2], At8[4][2];
#pragma unroll
  for (int rt = 0; rt < 4; ++rt)
#pragma unroll
    for (int kt = 0; kt < 2; ++kt) {
      Aw[rt][kt] = *(const short8*)(G + (16*rt + n16)*128 +      32*kt + quad*8);
      Ap[rt][kt] = *(const short8*)(G + (16*rt + n16)*128 + 64 + 32*kt + quad*8);
      At[rt][kt] = *(const short8*)(G + (64 + 16*rt + n16)*128 +      32*kt + quad*8);
      Av[rt][kt] = *(const short8*)(G + (64 + 16*rt + n16)*128 + 64 + 32*kt + quad*8);
    }
  for (int idx = t; idx < 4096; idx += 512) {
    const int r = idx >> 6, cj = idx & 63;
    scrA[r*SCR_STR + cj] = bf2f(G[(64 + r)*128 + cj]);
  }
  __syncthreads();

  // ---------------- T8 = T^8 via 3 squarings ----------------
  SQ_LEVEL(scrA, scrB); __syncthreads();   // T2
  SQ_LEVEL(scrB, scrA); __syncthreads();   // T4
  SQ_LEVEL(scrA, scrB); __syncthreads();   // T8
#pragma unroll
  for (int rt = 0; rt < 4; ++rt)
#pragma unroll
    for (int kt = 0; kt < 2; ++kt) {
      union { short8 v; unsigned short us[8]; } ua;
#pragma unroll
      for (int j = 0; j < 8; ++j)
        ua.us[j] = (short)f2bfru(scrB[(16*rt + n16)*SCR_STR + 32*kt + 8*quad + j]);
      At8[rt][kt] = ua.v;
    }
  __syncthreads();   // scratch + G dead -> slots usable

  // ---------------- Phase A: 8 chunks/wave, float4 + DPP transpose ----------------
  short8 UB[8][2];
  const float* ubase = u + (size_t)bq * ((size_t)SL * DM) + 4*h;
  const int tof = 8*quad + cc;
  const int q0  = w * 512;                  // first row of wave's chunk group
  char* myslots = lds + w * 16384;          // slots 8w..8w+7

  {
    float4 vA[2][2], vB[2][2], vC[2][2];
    LOADC(0, vA); LOADC(1, vB); LOADC(2, vC);
    PROCC(0, vA); LOADC(3, vA);
    PROCC(1, vB); LOADC(4, vB);
    PROCC(2, vC); LOADC(5, vC);
    PROCC(3, vA); LOADC(6, vA);
    PROCC(4, vB); LOADC(7, vB);
    PROCC(5, vC);
    PROCC(6, vA);
    PROCC(7, vB);
  }

  // ---------------- pass1: local scan -> group Rsum (pk) -> Gsum[w] ----------------
  const short8 Z8 = {0,0,0,0,0,0,0,0};
  short8 B0 = Z8, B1 = Z8;
  const int srcA = n16 + 16*((2*quad) & 3);
  const int srcB = n16 + 16*((2*quad + 1) & 3);
  const bool hi = (quad >= 2);
  char* gsw = lds + LDS_GSUM + w*2048;
#pragma unroll 1
  for (int j = 0; j < 8; ++j) {
    char* sp = myslots + j*2048;
    SCAN_STEP(sp, At, false, (j == 7), gsw);
  }
  __syncthreads();

  // ---------------- pass2: wave 0 scans group summaries with T8 ----------------
  if (w == 0) {
    B0 = Z8; B1 = Z8;
#pragma unroll 1
    for (int g = 0; g < 8; ++g) {
      char* gp = lds + LDS_GSUM + g*2048;
      SCAN_STEP(gp, At8, true, false, gp);   // reads Rsum_g, writes entering S_g
    }
  }
  __syncthreads();

  // ---------------- pass3 + Phase C fused ----------------
  {
    char* gpw = lds + LDS_GSUM + w*2048;
    B0 = *(const short8*)(gpw + lane*16);
    B1 = *(const short8*)(gpw + 1024 + lane*16);
  }
  const int rbl = 4*quad + cc;
  float* obase = out + (size_t)bq * ((size_t)SL * DM) + 4*h;
#pragma unroll
  for (int j = 0; j < 8; ++j) {
    char* sp = myslots + j*2048;
    // Y_q = Toep@U_q + W@S_q (entering state in B0/B1), DPP transpose, store
#pragma unroll
    for (int rt = 0; rt < 4; ++rt) {
      floatx4 ty = {0.f, 0.f, 0.f, 0.f};
      ty = __builtin_amdgcn_mfma_f32_16x16x32_bf16(Ap[rt][0], UB[j][0], ty, 0,0,0);
      ty = __builtin_amdgcn_mfma_f32_16x16x32_bf16(Ap[rt][1], UB[j][1], ty, 0,0,0);
      ty = __builtin_amdgcn_mfma_f32_16x16x32_bf16(Aw[rt][0], B0,       ty, 0,0,0);
      ty = __builtin_amdgcn_mfma_f32_16x16x32_bf16(Aw[rt][1], B1,       ty, 0,0,0);
      float4 yv; yv.x = ty[0]; yv.y = ty[1]; yv.z = ty[2]; yv.w = ty[3];
      float4 tw = qtr(yv, cc);
      *(float4*)(obase + (size_t)(q0 + j*64 + 16*rt + rbl) * DM) = tw;
    }
    // scan update: S' = T@S + R_q
    SCAN_STEP(sp, At, false, false, sp);
  }
}

// ---------------------------------------------------------------- launch --
extern "C" void kernel_launch(void* const* d_in, const int* in_sizes, int n_in,
                              void* d_out, int out_size, void* d_ws, size_t ws_size,
                              hipStream_t stream)
{
  const float* u = (const float*)d_in[0];
  const float* a = (const float*)d_in[1];
  const float* b = (const float*)d_in[2];
  const float* c = (const float*)d_in[3];
  float* out = (float*)d_out;
  (void)d_ws; (void)ws_size; (void)in_sizes; (void)n_in; (void)out_size;

  fused_kernel<<<NKH, 512, 0, stream>>>(u, a, b, c, out);
}